// Round 15
// baseline (1270.149 us; speedup 1.0000x reference)
//
#include <hip/hip_runtime.h>

// Problem constants
#define TSTEPS 128
#define NCLS 11
#define BTILE 8
// ws layout (floats):
//  [0, WTOT): octet-interleaved, gate-PAIR-interleaved weights:
//    idx = (tid>>3)*896 + chunk*32 + (tid&7)*4 + kk   (chunk stride 128B -> all
//    loads from ONE base at immediate offset chunk*128; a wave-load is 8
//    contiguous 128B lines)
//    L1 chunks 0..15: chunk = p*8 + j*2 + h  (p = gate pair: 0={i,f},1={g,o})
//      float4 = (gA[c], gB[c], gA[c+1], gB[c+1]), c = 4*(s+8j)+2h, s=tid&7,
//      d=tid>>3, from Whh1[(gate*128+d)*128 + col]   [pair-interleaved for pk_fma]
//    L2 chunks 16..27: chunk = 16 + p*6 + j*2 + h, s2=tid&15, d2=tid>>4,
//      col = 4*(s2+16j)+2h+(kk>>1); col<128 -> Wih2[row][col] else Whh2[row][col-128]
//  [WTOT, WTOT+WFCF): packed FC weights wsF[t][d2][16]:
//    slots 0..5 = Wfc[0..5][t*64+d2], slots 8..12 = Wfc[6..10][t*64+d2] (rest 0)
#define WTOT 114688
#define WFCF 131072

typedef float f32x2 __attribute__((ext_vector_type(2)));
typedef float f32x4 __attribute__((ext_vector_type(4)));

__device__ __forceinline__ float rcpf_(float x) { return __builtin_amdgcn_rcpf(x); }
__device__ __forceinline__ float sigm(float x) { return rcpf_(1.0f + __expf(-x)); }
__device__ __forceinline__ float tanhf_(float x) { return 1.0f - 2.0f * rcpf_(__expf(2.0f * x) + 1.0f); }

// v_pk_fma_f32 (CDNA dual-FP32): acc.x += w.x*h.sel; acc.y += w.y*h.sel
// pk_lo broadcasts h.x to both halves, pk_hi broadcasts h.y.
__device__ __forceinline__ void pk_lo(f32x2& acc, f32x2 w, f32x2 h) {
    asm("v_pk_fma_f32 %0, %1, %2, %0 op_sel:[0,0,0] op_sel_hi:[1,0,1]"
        : "+v"(acc) : "v"(w), "v"(h));
}
__device__ __forceinline__ void pk_hi(f32x2& acc, f32x2 w, f32x2 h) {
    asm("v_pk_fma_f32 %0, %1, %2, %0 op_sel:[0,1,0] op_sel_hi:[1,1,1]"
        : "+v"(acc) : "v"(w), "v"(h));
}
#define SV2(v, a, b) __builtin_shufflevector((v), (v), (a), (b))

// DPP lane exchange on VALU.
// 0xB1 = quad_perm[1,0,3,2] (xor1), 0x4E = quad_perm[2,3,0,1] (xor2),
// 0x141 = row_half_mirror (index-symmetric stages only: partner 7-s sends the
//         same array slot), 0x128 = row_ror:8 (true lane^8 within each 16).
template <int CTRL>
__device__ __forceinline__ float dppf(float x) {
    return __int_as_float(__builtin_amdgcn_update_dpp(
        0, __float_as_int(x), CTRL, 0xF, 0xF, true));
}
template <int CTRL>
__device__ __forceinline__ f32x2 dpp2(f32x2 v) {
    f32x2 r;
    r.x = dppf<CTRL>(v.x);
    r.y = dppf<CTRL>(v.y);
    return r;
}

__global__ void prep_weights(const float* __restrict__ Whh1,
                             const float* __restrict__ Wih2,
                             const float* __restrict__ Whh2,
                             const float* __restrict__ Wfc,
                             float* __restrict__ ws, int packFc) {
    int idx = blockIdx.x * blockDim.x + threadIdx.x;
    if (idx < WTOT) {
        int idx4 = idx >> 2, kk = idx & 3;
        int oct = idx4 / 224;
        int r4 = idx4 - oct * 224;
        int chunk = r4 >> 3;
        int tid = oct * 8 + (r4 & 7);
        float v;
        if (chunk < 16) {
            int p = chunk >> 3, rem = chunk & 7, j = rem >> 1, h = rem & 1;
            int s = tid & 7, d = tid >> 3;
            int gate = 2 * p + (kk & 1);
            int col = 4 * (s + 8 * j) + 2 * h + (kk >> 1);
            v = Whh1[(gate * 128 + d) * 128 + col];
        } else {
            int c2 = chunk - 16;
            int p = c2 / 6, rem = c2 - 6 * p, j = rem >> 1, h = rem & 1;
            int s2 = tid & 15, d2 = tid >> 4;
            int gate = 2 * p + (kk & 1);
            int col = 4 * (s2 + 16 * j) + 2 * h + (kk >> 1);
            int row = gate * 64 + d2;
            v = (col < 128) ? Wih2[row * 128 + col] : Whh2[row * 64 + (col - 128)];
        }
        ws[idx] = v;
    } else if (packFc && idx < WTOT + WFCF) {
        int r = idx - WTOT;
        int t = r >> 10;
        int rem = r & 1023;
        int d2 = rem >> 4, slot = rem & 15;
        float v = 0.0f;
        if (slot < 6) v = Wfc[slot * 8192 + t * 64 + d2];
        else if (slot >= 8 && slot <= 12) v = Wfc[(slot - 2) * 8192 + t * 64 + d2];
        ws[idx] = v;
    }
}

// Persistent fused 2-layer LSTM + FC. grid=256 (1 block/CU), block=1024 (16 waves).
// r1-r14 established: immovable 64-VGPR budget (FETCH_SIZE is the spill canary);
// r12 (VALU halved) and r14 (DS halved, L2 doubled) were both TIME-NEUTRAL ->
// the kernel sits on a DS/L2 balance frontier. Pipe model (cyc/CU-step):
//   r11/r12: DS 21.5K, L2-W 14K    r14: DS 10.7K, L2-W 28K    (measured ~25-26K)
// r15 = the interior balance point, a literal merge of two verified kernels
// over the SAME prep layout:
//   L1 = r12's two-pass pair-split (DS 64 reads, W 256 B/thread)
//   L2 = r14's fused-pairs b-blocked (DS 24 reads, W 384 B/thread)
// -> DS 88 reads = 16.9K (-21% off the dominant pipe), W 640 B = 11.7-20.5K.
// Max-model predicts ~1050-1150 us; if >= 1215 (r11 best) the structural floor
// of this decomposition is established.
__global__ __attribute__((amdgpu_flat_work_group_size(1024, 1024),
                          amdgpu_waves_per_eu(4, 4)))
void lstm_fused_t(const float* __restrict__ x, const float* __restrict__ Wih1,
                  const float* __restrict__ Wfc, const float* __restrict__ bfc,
                  const float* __restrict__ ws, float* __restrict__ out, int packed) {

    __shared__ __align__(16) float lx[BTILE][2 * TSTEPS + 4];  // x staged [b][c*128+t]
    __shared__ __align__(16) float lh1[2][BTILE][128];         // h1 double buffer
    __shared__ __align__(16) float lh2[2][BTILE][64];          // h2 double buffer
    __shared__ __align__(16) float4 lwih4[2][128];             // [0][d]=(ia,ib,fa,fb) [1][d]=(ga,gb,oa,ob)
    __shared__ float lfacc[1024][7];                           // per-thread FC accumulators (6 used)
    __shared__ float fpart[16][BTILE][NCLS];                   // per-wave FC partials (epilogue)

    const int tid = threadIdx.x;
    const int b0 = blockIdx.x * BTILE;

    for (int i = tid; i < BTILE * 2 * TSTEPS; i += 1024)
        lx[i >> 8][i & 255] = x[b0 * 256 + i];
    for (int i = tid; i < 2 * BTILE * 128; i += 1024)
        ((float*)lh1)[i] = 0.0f;
    if (tid < 2 * BTILE * 64) ((float*)lh2)[tid] = 0.0f;
    for (int i = tid; i < 1024 * 7; i += 1024)
        ((float*)lfacc)[i] = 0.0f;
    if (tid < 128) {
        const float2* wp = (const float2*)Wih1;   // row r -> float2 at index r
        const float2 ri = wp[tid], rf = wp[128 + tid], rg = wp[256 + tid], ro = wp[384 + tid];
        lwih4[0][tid] = make_float4(ri.x, ri.y, rf.x, rf.y);
        lwih4[1][tid] = make_float4(rg.x, rg.y, ro.x, ro.y);
    }

    const int d  = tid >> 3;
    const int s_ = tid & 7;
    const int d2 = tid >> 4;
    const int s2 = tid & 15;
    const bool lowh = (s2 < 8);

    // single weight base: all 28 chunk loads at immediate offset chunk*128 bytes
    const f32x4* __restrict__ wqt = (const f32x4*)ws + ((tid >> 3) * 224 + (tid & 7));
    const float* __restrict__ wfcPk = ws + WTOT + ((d2 << 4) + (lowh ? 0 : 8));

    float c1 = 0.0f, c2v = 0.0f;

    __syncthreads();

#pragma unroll 1
    for (int t = 0; t < TSTEPS; ++t) {
        const int tb = t & 1;        // h_t buffer
        const int xb = tb ^ 1;       // h_{t-1} buffer
        const bool f4 = (s_ & 4) != 0;
        const bool f2 = (s_ & 2) != 0;
        const bool f1 = (s_ & 1) != 0;

        // ======== layer 1, pass A (r12): gates i,f over K-slice s, all 8 b ========
        f32x2 rif;
        {
            f32x2 AB[8];
#pragma unroll
            for (int b = 0; b < 8; ++b) AB[b] = (f32x2){0.0f, 0.0f};
#pragma unroll
            for (int j = 0; j < 4; ++j) {
                const f32x4 c0 = wqt[(2 * j) * 8];       // (i0,f0,i1,f1)
                const f32x4 ch = wqt[(2 * j + 1) * 8];   // (i2,f2,i3,f3)
                const int ko = 4 * (s_ + 8 * j);
#pragma unroll
                for (int b = 0; b < 8; ++b) {
                    const f32x4 h4 = *(const f32x4*)&lh1[xb][b][ko];  // broadcast, conflict-free
                    const f32x2 h01 = SV2(h4, 0, 1), h23 = SV2(h4, 2, 3);
                    pk_lo(AB[b], SV2(c0, 0, 1), h01);
                    pk_hi(AB[b], SV2(c0, 2, 3), h01);
                    pk_lo(AB[b], SV2(ch, 0, 1), h23);
                    pk_hi(AB[b], SV2(ch, 2, 3), h23);
                }
            }
            f32x2 Aa[4];
#pragma unroll
            for (int i = 0; i < 4; ++i)
                Aa[i] = (f4 ? AB[i+4] : AB[i]) + dpp2<0x141>(f4 ? AB[i] : AB[i+4]);
            f32x2 Ba[2];
#pragma unroll
            for (int i = 0; i < 2; ++i)
                Ba[i] = (f2 ? Aa[i+2] : Aa[i]) + dpp2<0x4E>(f2 ? Aa[i] : Aa[i+2]);
            rif = (f1 ? Ba[1] : Ba[0]) + dpp2<0xB1>(f1 ? Ba[0] : Ba[1]);
        }
        __builtin_amdgcn_sched_barrier(0);   // keep pass B's loads out of pass A

        // ======== layer 1, pass B (r12): gates g,o ========
        f32x2 rgo;
        {
            f32x2 AB[8];
#pragma unroll
            for (int b = 0; b < 8; ++b) AB[b] = (f32x2){0.0f, 0.0f};
#pragma unroll
            for (int j = 0; j < 4; ++j) {
                const f32x4 c0 = wqt[(8 + 2 * j) * 8];
                const f32x4 ch = wqt[(9 + 2 * j) * 8];
                const int ko = 4 * (s_ + 8 * j);
#pragma unroll
                for (int b = 0; b < 8; ++b) {
                    const f32x4 h4 = *(const f32x4*)&lh1[xb][b][ko];
                    const f32x2 h01 = SV2(h4, 0, 1), h23 = SV2(h4, 2, 3);
                    pk_lo(AB[b], SV2(c0, 0, 1), h01);
                    pk_hi(AB[b], SV2(c0, 2, 3), h01);
                    pk_lo(AB[b], SV2(ch, 0, 1), h23);
                    pk_hi(AB[b], SV2(ch, 2, 3), h23);
                }
            }
            f32x2 Aa[4];
#pragma unroll
            for (int i = 0; i < 4; ++i)
                Aa[i] = (f4 ? AB[i+4] : AB[i]) + dpp2<0x141>(f4 ? AB[i] : AB[i+4]);
            f32x2 Ba[2];
#pragma unroll
            for (int i = 0; i < 2; ++i)
                Ba[i] = (f2 ? Aa[i+2] : Aa[i]) + dpp2<0x4E>(f2 ? Aa[i] : Aa[i+2]);
            rgo = (f1 ? Ba[1] : Ba[0]) + dpp2<0xB1>(f1 ? Ba[0] : Ba[1]);
        }
        __builtin_amdgcn_sched_barrier(0);

        // elementwise for (b = s, d) — all 1024 threads are owners.
        // Wih1 from LDS each step; opaque zero index defeats LICM hoisting.
        int zr; asm volatile("v_mov_b32 %0, 0" : "=v"(zr));
        const float4 wv0 = lwih4[0][d + zr];
        const float4 wv1 = lwih4[1][d + zr];
        const float x0 = lx[s_][t], x1 = lx[s_][TSTEPS + t];
        const float gi = rif.x + wv0.x * x0 + wv0.y * x1;
        const float gf = rif.y + wv0.z * x0 + wv0.w * x1;
        const float gg = rgo.x + wv1.x * x0 + wv1.y * x1;
        const float go = rgo.y + wv1.z * x0 + wv1.w * x1;
        const float i1 = sigm(gi), ff = sigm(gf), g1v = tanhf_(gg), o1 = sigm(go);
        c1 = ff * c1 + i1 * g1v;
        const float h1n = o1 * tanhf_(c1);

        lh1[tb][s_][d] = h1n;            // double-buffered: no pre-write barrier needed
        __syncthreads();                 // the ONLY barrier per step

        const bool g8 = (s2 & 8) != 0;
        const bool e4 = (s2 & 4) != 0;
        const bool e2 = (s2 & 2) != 0;
        const bool e1 = (s2 & 1) != 0;

        // ======== layer 2 (r14): BOTH gate pairs, b-blocked, K = 192 ========
        float DA, EA, DB, EB;
        {
            f32x2 QifX, QgoX, Qif, Qgo;
#pragma unroll
            for (int blk = 0; blk < 2; ++blk) {
                f32x2 uif[2][2], ugo[2][2];
#pragma unroll
                for (int k = 0; k < 2; ++k)
#pragma unroll
                    for (int i = 0; i < 2; ++i) {
                        uif[k][i] = (f32x2){0.0f, 0.0f};
                        ugo[k][i] = (f32x2){0.0f, 0.0f};
                    }
#pragma unroll
                for (int j = 0; j < 3; ++j) {
                    const f32x4 wa0 = wqt[(16 + 2 * j) * 8];  // pair {i,f}
                    const f32x4 wa1 = wqt[(17 + 2 * j) * 8];
                    const f32x4 wb0 = wqt[(22 + 2 * j) * 8];  // pair {g,o}
                    const f32x4 wb1 = wqt[(23 + 2 * j) * 8];
#pragma unroll
                    for (int k = 0; k < 2; ++k)
#pragma unroll
                        for (int i = 0; i < 2; ++i) {
                            const int b = 4 * k + i + 2 * blk;
                            const f32x4 h4 = (j < 2)
                                ? *(const f32x4*)&lh1[tb][b][4 * s2 + 64 * j]
                                : *(const f32x4*)&lh2[xb][b][4 * s2];
                            const f32x2 h01 = SV2(h4, 0, 1), h23 = SV2(h4, 2, 3);
                            pk_lo(uif[k][i], SV2(wa0, 0, 1), h01);
                            pk_hi(uif[k][i], SV2(wa0, 2, 3), h01);
                            pk_lo(uif[k][i], SV2(wa1, 0, 1), h23);
                            pk_hi(uif[k][i], SV2(wa1, 2, 3), h23);
                            pk_lo(ugo[k][i], SV2(wb0, 0, 1), h01);
                            pk_hi(ugo[k][i], SV2(wb0, 2, 3), h01);
                            pk_lo(ugo[k][i], SV2(wb1, 0, 1), h23);
                            pk_hi(ugo[k][i], SV2(wb1, 2, 3), h23);
                        }
                }
                // in-block reduce: bit2 (mirror, index-symmetric) then bit0 (xor1)
                f32x2 U[2], V[2];
#pragma unroll
                for (int i = 0; i < 2; ++i) {
                    U[i] = (e4 ? uif[1][i] : uif[0][i]) + dpp2<0x141>(e4 ? uif[0][i] : uif[1][i]);
                    V[i] = (e4 ? ugo[1][i] : ugo[0][i]) + dpp2<0x141>(e4 ? ugo[0][i] : ugo[1][i]);
                }
                const f32x2 qif = (e1 ? U[1] : U[0]) + dpp2<0xB1>(e1 ? U[0] : U[1]);
                const f32x2 qgo = (e1 ? V[1] : V[0]) + dpp2<0xB1>(e1 ? V[0] : V[1]);
                if (blk == 0) {
                    QifX = qif; QgoX = qgo;
                } else {
                    Qif = (e2 ? qif : QifX) + dpp2<0x4E>(e2 ? QifX : qif);
                    Qgo = (e2 ? qgo : QgoX) + dpp2<0x4E>(e2 ? QgoX : qgo);
                }
                __builtin_amdgcn_sched_barrier(0);
            }
            // gate-pair split via true xor8 (lane^8 within 16) — moved to the end
            DA = (g8 ? Qif.y : Qif.x) + dppf<0x128>(g8 ? Qif.x : Qif.y);
            EA = dppf<0x128>(DA);
            DB = (g8 ? Qgo.y : Qgo.x) + dppf<0x128>(g8 ? Qgo.x : Qgo.y);
            EB = dppf<0x128>(DB);
        }
        // lanes s2<8: i=DA, f=EA, g=DB, o=EB; lanes s2>=8: i=EA, f=DA, g=EB, o=DB (b = s2&7)

        const float gi2 = lowh ? DA : EA;
        const float gf2 = lowh ? EA : DA;
        const float gg2 = lowh ? DB : EB;
        const float go2 = lowh ? EB : DB;
        const float i2 = sigm(gi2), f2g = sigm(gf2), g2v = tanhf_(gg2), o2 = sigm(go2);
        c2v = f2g * c2v + i2 * g2v;               // both lane-halves keep identical c2
        const float h2n = o2 * tanhf_(c2v);
        // fused FC into LDS accumulators, classes split: lower lanes 0..5, upper 6..10
        if (packed) {
            const float* fp = wfcPk + (t << 10);
            const float4 fa = *(const float4*)fp;
            const float2 fb = *(const float2*)(fp + 4);
            lfacc[tid][0] += h2n * fa.x;
            lfacc[tid][1] += h2n * fa.y;
            lfacc[tid][2] += h2n * fa.z;
            lfacc[tid][3] += h2n * fa.w;
            lfacc[tid][4] += h2n * fb.x;
            if (lowh) lfacc[tid][5] += h2n * fb.y;
        } else {
            const float* wfcp = Wfc + t * 64 + d2 + (lowh ? 0 : 6 * 8192);
            if (lowh) {
#pragma unroll
                for (int c = 0; c < 6; ++c) lfacc[tid][c] += h2n * wfcp[c * 8192];
            } else {
#pragma unroll
                for (int c = 0; c < 5; ++c) lfacc[tid][c] += h2n * wfcp[c * 8192];
            }
        }
        if (lowh) lh2[tb][s2][d2] = h2n;   // double-buffered: next read is after B(t+1)
    }

    // final FC reduction: pull per-thread accumulators back to regs, sum over the
    // 4 in-wave d2 groups (lane bits 4,5 — cross-row, keep __shfl_xor), then
    // across the 16 waves via LDS.
    float facc[6];
#pragma unroll
    for (int c = 0; c < 6; ++c) facc[c] = lfacc[tid][c];
#pragma unroll
    for (int c = 0; c < 6; ++c) {
        facc[c] += __shfl_xor(facc[c], 16);
        facc[c] += __shfl_xor(facc[c], 32);
    }
    const int wv = tid >> 6;
    if ((tid & 63) < 16) {
        const int bb = tid & 7;
        if ((tid & 15) < 8) {
#pragma unroll
            for (int c = 0; c < 6; ++c) fpart[wv][bb][c] = facc[c];
        } else {
#pragma unroll
            for (int c = 0; c < 5; ++c) fpart[wv][bb][6 + c] = facc[c];
        }
    }
    __syncthreads();
    if (tid < BTILE * NCLS) {
        const int bb = tid / NCLS, c = tid - bb * NCLS;
        float v = bfc[c];
#pragma unroll
        for (int w = 0; w < 16; ++w) v += fpart[w][bb][c];
        out[(b0 + bb) * NCLS + c] = v;
    }
}

extern "C" void kernel_launch(void* const* d_in, const int* in_sizes, int n_in,
                              void* d_out, int out_size, void* d_ws, size_t ws_size,
                              hipStream_t stream) {
    const float* x    = (const float*)d_in[0];
    const float* Wih1 = (const float*)d_in[1];
    const float* Whh1 = (const float*)d_in[2];
    const float* Wih2 = (const float*)d_in[3];
    const float* Whh2 = (const float*)d_in[4];
    const float* Wfc  = (const float*)d_in[5];
    const float* bfc  = (const float*)d_in[6];
    float* out = (float*)d_out;
    float* ws  = (float*)d_ws;

    const int packed = (ws_size >= (size_t)(WTOT + WFCF) * 4) ? 1 : 0;
    const int prep_elems = WTOT + (packed ? WFCF : 0);   // 448 KB (+512 KB packed FC)
    prep_weights<<<(prep_elems + 255) / 256, 256, 0, stream>>>(Whh1, Wih2, Whh2, Wfc, ws, packed);
    lstm_fused_t<<<256, 1024, 0, stream>>>(x, Wih1, Wfc, bfc, ws, out, packed);
}

// Round 16
// 1209.869 us; speedup vs baseline: 1.0498x; 1.0498x over previous
//
#include <hip/hip_runtime.h>

// Problem constants
#define TSTEPS 128
#define NCLS 11
#define BTILE 8
// ws layout (floats):
//  [0, WTOT): quad-interleaved weights: idx = (tid>>2)*448 + chunk*16 + (tid&3)*4 + kk
//    chunk 0..15  (L1): g = chunk>>2 (gate), j = chunk&3, s = tid&7, d = tid>>3,
//                       val = Whh1[(g*128+d)*128 + 4*(s+8j)+kk]
//    chunk 16..27 (L2): c2 = chunk-16, g = c2/3, j = c2%3, s = tid&15, d2 = tid>>4,
//                       col = 4*(s+16j)+kk; col<128 -> Wih2[g*64+d2][col] else Whh2[...][col-128]
//    => in-kernel: ONE base address/thread, all loads at immediate offset chunk*64B.
//  [WTOT, WTOT+WFCF): packed FC weights wsF[t][d2][16]:
//    slots 0..5 = Wfc[0..5][t*64+d2], slots 8..12 = Wfc[6..10][t*64+d2] (rest 0)
#define WTOT 114688
#define WFCF 131072

__device__ __forceinline__ float rcpf_(float x) { return __builtin_amdgcn_rcpf(x); }
// v_rcp_f32-based (1 ULP) — IEEE '/' emits an ~11-op div sequence without fast-math.
__device__ __forceinline__ float sigm(float x) { return rcpf_(1.0f + __expf(-x)); }
__device__ __forceinline__ float tanhf_(float x) { return 1.0f - 2.0f * rcpf_(__expf(2.0f * x) + 1.0f); }

// DPP lane exchange on VALU.
// ctrl: 0xB1 = quad_perm[1,0,3,2] (xor1), 0x4E = quad_perm[2,3,0,1] (xor2),
//       0x141 = row_half_mirror (p <-> 7-p within each 8; flips lane bit2),
//       0x128 = row_ror:8 (c <-> c^8 within each 16).
template <int CTRL>
__device__ __forceinline__ float dppf(float x) {
    return __int_as_float(__builtin_amdgcn_update_dpp(
        0, __float_as_int(x), CTRL, 0xF, 0xF, true));
}

__global__ void prep_weights(const float* __restrict__ Whh1,
                             const float* __restrict__ Wih2,
                             const float* __restrict__ Whh2,
                             const float* __restrict__ Wfc,
                             float* __restrict__ ws, int packFc) {
    int idx = blockIdx.x * blockDim.x + threadIdx.x;
    if (idx < WTOT) {
        int q = idx / 448;
        int r = idx % 448;
        int chunk = r >> 4;
        int lane = (r >> 2) & 3;
        int kk = idx & 3;
        int tid = q * 4 + lane;
        float v;
        if (chunk < 16) {
            int s = tid & 7, dd = tid >> 3, g = chunk >> 2, j = chunk & 3;
            v = Whh1[(g * 128 + dd) * 128 + 4 * (s + 8 * j) + kk];
        } else {
            int c2 = chunk - 16;
            int g = c2 / 3, j = c2 - 3 * g;
            int s = tid & 15, d2 = tid >> 4;
            int col = 4 * (s + 16 * j) + kk;
            int row = g * 64 + d2;
            v = (col < 128) ? Wih2[row * 128 + col] : Whh2[row * 64 + (col - 128)];
        }
        ws[idx] = v;
    } else if (packFc && idx < WTOT + WFCF) {
        int r = idx - WTOT;
        int t = r >> 10;
        int rem = r & 1023;
        int d2 = rem >> 4, slot = rem & 15;
        float v = 0.0f;
        if (slot < 6) v = Wfc[slot * 8192 + t * 64 + d2];
        else if (slot >= 8 && slot <= 12) v = Wfc[(slot - 2) * 8192 + t * 64 + d2];
        ws[idx] = v;
    }
}

#define DOT4(acc, q, h) (acc += (q).x*(h).x + (q).y*(h).y + (q).z*(h).z + (q).w*(h).w)

// Persistent fused 2-layer LSTM + FC. grid=256 (1 block/CU), block=1024 (16 waves).
// FINAL (r16 = r11 revert): verified-best configuration at 1215 us.
// Established over r1-r15: immovable 64-VGPR budget for 1024-thread kernels ->
// gate-pair split MACs, Wih1 + FC accums in LDS, single weight base + immediate
// offsets (quad-interleaved), DPP butterflies, double-buffered lh1/lh2 (ONE
// barrier/step), v_rcp transcendentals. Scratch = 0 (FETCH = inputs only).
// Post-r11 probes: pk_fma −47% VALU (r12, neutral), fused-pairs −50% DS (r14,
// neutral), interior balance (r15, worse), 2-step unroll (r13, re-spilled).
// Conclusion: issue/dependency-latency floor of the barrier-synced sequential
// recurrence at 4 waves/SIMD — no pipe-throughput lever remains.
__global__ __attribute__((amdgpu_flat_work_group_size(1024, 1024),
                          amdgpu_waves_per_eu(4, 4)))
void lstm_fused_t(const float* __restrict__ x, const float* __restrict__ Wih1,
                  const float* __restrict__ Wfc, const float* __restrict__ bfc,
                  const float* __restrict__ ws, float* __restrict__ out, int packed) {

    __shared__ __align__(16) float lx[BTILE][2 * TSTEPS + 4];  // x staged [b][c*128+t]
    __shared__ __align__(16) float lh1[2][BTILE][128];         // h1 double buffer
    __shared__ __align__(16) float lh2[2][BTILE][64];          // h2 double buffer
    __shared__ __align__(16) float4 lwih4[2][128];             // [0][d]=(ia,ib,fa,fb) [1][d]=(ga,gb,oa,ob)
    __shared__ float lfacc[1024][7];                           // per-thread FC accumulators (6 used)
    __shared__ float fpart[16][BTILE][NCLS];                   // per-wave FC partials (epilogue)

    const int tid = threadIdx.x;
    const int b0 = blockIdx.x * BTILE;

    for (int i = tid; i < BTILE * 2 * TSTEPS; i += 1024)
        lx[i >> 8][i & 255] = x[b0 * 256 + i];
    for (int i = tid; i < 2 * BTILE * 128; i += 1024)
        ((float*)lh1)[i] = 0.0f;
    if (tid < 2 * BTILE * 64) ((float*)lh2)[tid] = 0.0f;
    for (int i = tid; i < 1024 * 7; i += 1024)
        ((float*)lfacc)[i] = 0.0f;
    if (tid < 128) {
        const float2* wp = (const float2*)Wih1;   // row r -> float2 at index r
        const float2 ri = wp[tid], rf = wp[128 + tid], rg = wp[256 + tid], ro = wp[384 + tid];
        lwih4[0][tid] = make_float4(ri.x, ri.y, rf.x, rf.y);
        lwih4[1][tid] = make_float4(rg.x, rg.y, ro.x, ro.y);
    }

    const int d  = tid >> 3;
    const int s  = tid & 7;
    const int d2 = tid >> 4;
    const int s2 = tid & 15;
    const bool lowh = (s2 < 8);

    // single weight base: all 28 chunk loads at immediate offset chunk*64 bytes
    const float4* __restrict__ wqt = (const float4*)ws + ((tid >> 2) * 112 + (tid & 3));
    const float* __restrict__ wfcPk = ws + WTOT + ((d2 << 4) + (lowh ? 0 : 8));

    float c1 = 0.0f, c2 = 0.0f;

    __syncthreads();

#pragma unroll 1
    for (int t = 0; t < TSTEPS; ++t) {
        const int tb = t & 1;        // h_t buffer
        const int xb = tb ^ 1;       // h_{t-1} buffer
        const bool f4 = (s & 4) != 0;
        const bool f2 = (s & 2) != 0;
        const bool f1 = (s & 1) != 0;

        // ======== layer 1, pass A: gates i,f over K-slice s (16 accumulators) ========
        float ri, rf_;
        {
            float va[8], vb[8];
#pragma unroll
            for (int b = 0; b < 8; ++b) { va[b] = vb[b] = 0.0f; }
#pragma unroll
            for (int j = 0; j < 4; ++j) {
                const float4 qa = wqt[(0 + j) * 4];   // gate i
                const float4 qb = wqt[(4 + j) * 4];   // gate f
                const int ko = 4 * (s + 8 * j);
#pragma unroll
                for (int b = 0; b < 8; ++b) {
                    const float4 h4 = *(const float4*)&lh1[xb][b][ko];  // broadcast, conflict-free
                    DOT4(va[b], qa, h4);
                    DOT4(vb[b], qb, h4);
                }
            }
            float Aa[4], Ab[4];
#pragma unroll
            for (int i = 0; i < 4; ++i) {
                Aa[i] = (f4 ? va[i+4] : va[i]) + dppf<0x141>(f4 ? va[i] : va[i+4]);
                Ab[i] = (f4 ? vb[i+4] : vb[i]) + dppf<0x141>(f4 ? vb[i] : vb[i+4]);
            }
            float Ba[2], Bb[2];
#pragma unroll
            for (int i = 0; i < 2; ++i) {
                Ba[i] = (f2 ? Aa[i+2] : Aa[i]) + dppf<0x4E>(f2 ? Aa[i] : Aa[i+2]);
                Bb[i] = (f2 ? Ab[i+2] : Ab[i]) + dppf<0x4E>(f2 ? Ab[i] : Ab[i+2]);
            }
            ri  = (f1 ? Ba[1] : Ba[0]) + dppf<0xB1>(f1 ? Ba[0] : Ba[1]);
            rf_ = (f1 ? Bb[1] : Bb[0]) + dppf<0xB1>(f1 ? Bb[0] : Bb[1]);
        }
        __builtin_amdgcn_sched_barrier(0);   // keep pass B's loads out of pass A

        // ======== layer 1, pass B: gates g,o ========
        float rg, ro;
        {
            float va[8], vb[8];
#pragma unroll
            for (int b = 0; b < 8; ++b) { va[b] = vb[b] = 0.0f; }
#pragma unroll
            for (int j = 0; j < 4; ++j) {
                const float4 qa = wqt[(8  + j) * 4];  // gate g
                const float4 qb = wqt[(12 + j) * 4];  // gate o
                const int ko = 4 * (s + 8 * j);
#pragma unroll
                for (int b = 0; b < 8; ++b) {
                    const float4 h4 = *(const float4*)&lh1[xb][b][ko];
                    DOT4(va[b], qa, h4);
                    DOT4(vb[b], qb, h4);
                }
            }
            float Aa[4], Ab[4];
#pragma unroll
            for (int i = 0; i < 4; ++i) {
                Aa[i] = (f4 ? va[i+4] : va[i]) + dppf<0x141>(f4 ? va[i] : va[i+4]);
                Ab[i] = (f4 ? vb[i+4] : vb[i]) + dppf<0x141>(f4 ? vb[i] : vb[i+4]);
            }
            float Ba[2], Bb[2];
#pragma unroll
            for (int i = 0; i < 2; ++i) {
                Ba[i] = (f2 ? Aa[i+2] : Aa[i]) + dppf<0x4E>(f2 ? Aa[i] : Aa[i+2]);
                Bb[i] = (f2 ? Ab[i+2] : Ab[i]) + dppf<0x4E>(f2 ? Ab[i] : Ab[i+2]);
            }
            rg = (f1 ? Ba[1] : Ba[0]) + dppf<0xB1>(f1 ? Ba[0] : Ba[1]);
            ro = (f1 ? Bb[1] : Bb[0]) + dppf<0xB1>(f1 ? Bb[0] : Bb[1]);
        }
        __builtin_amdgcn_sched_barrier(0);

        // elementwise for (b = s, d) — all 1024 threads are owners.
        // Wih1 from LDS each step; opaque zero index defeats LICM hoisting.
        int zr; asm volatile("v_mov_b32 %0, 0" : "=v"(zr));
        const float4 wv0 = lwih4[0][d + zr];
        const float4 wv1 = lwih4[1][d + zr];
        const float x0 = lx[s][t], x1 = lx[s][TSTEPS + t];
        const float gi = ri  + wv0.x * x0 + wv0.y * x1;
        const float gf = rf_ + wv0.z * x0 + wv0.w * x1;
        const float gg = rg  + wv1.x * x0 + wv1.y * x1;
        const float go = ro  + wv1.z * x0 + wv1.w * x1;
        const float i1 = sigm(gi), ff = sigm(gf), g1v = tanhf_(gg), o1 = sigm(go);
        c1 = ff * c1 + i1 * g1v;
        const float h1n = o1 * tanhf_(c1);

        lh1[tb][s][d] = h1n;             // double-buffered: no pre-write barrier needed
        __syncthreads();                 // B: h1_t visible (the ONLY barrier per step)

        const bool g8 = (s2 & 8) != 0;
        const bool e4 = (s2 & 4) != 0;
        const bool e2 = (s2 & 2) != 0;
        const bool e1 = (s2 & 1) != 0;

        // ======== layer 2, pass A: gates i,f over K=192 slice s2 ========
        float DA, EA;
        {
            float ua[8], ub[8];
#pragma unroll
            for (int b = 0; b < 8; ++b) { ua[b] = ub[b] = 0.0f; }
#pragma unroll
            for (int j = 0; j < 3; ++j) {
                const float4 pa = wqt[(16 + j) * 4];  // gate i
                const float4 pb = wqt[(19 + j) * 4];  // gate f
#pragma unroll
                for (int b = 0; b < 8; ++b) {
                    const float4 h4 = (j < 2)
                        ? *(const float4*)&lh1[tb][b][4 * s2 + 64 * j]
                        : *(const float4*)&lh2[xb][b][4 * s2];
                    DOT4(ua[b], pa, h4);
                    DOT4(ub[b], pb, h4);
                }
            }
            float T[8];
#pragma unroll
            for (int b = 0; b < 8; ++b)
                T[b] = (g8 ? ub[b] : ua[b]) + dppf<0x128>(g8 ? ua[b] : ub[b]);
            float V[4];
#pragma unroll
            for (int i = 0; i < 4; ++i)
                V[i] = (e4 ? T[i+4] : T[i]) + dppf<0x141>(e4 ? T[i] : T[i+4]);
            float X[2];
#pragma unroll
            for (int i = 0; i < 2; ++i)
                X[i] = (e2 ? V[i+2] : V[i]) + dppf<0x4E>(e2 ? V[i] : V[i+2]);
            DA = (e1 ? X[1] : X[0]) + dppf<0xB1>(e1 ? X[0] : X[1]);
            EA = dppf<0x128>(DA);
        }
        __builtin_amdgcn_sched_barrier(0);

        // ======== layer 2, pass B: gates g,o ========
        float DB, EB;
        {
            float ua[8], ub[8];
#pragma unroll
            for (int b = 0; b < 8; ++b) { ua[b] = ub[b] = 0.0f; }
#pragma unroll
            for (int j = 0; j < 3; ++j) {
                const float4 pa = wqt[(22 + j) * 4];  // gate g
                const float4 pb = wqt[(25 + j) * 4];  // gate o
#pragma unroll
                for (int b = 0; b < 8; ++b) {
                    const float4 h4 = (j < 2)
                        ? *(const float4*)&lh1[tb][b][4 * s2 + 64 * j]
                        : *(const float4*)&lh2[xb][b][4 * s2];
                    DOT4(ua[b], pa, h4);
                    DOT4(ub[b], pb, h4);
                }
            }
            float T[8];
#pragma unroll
            for (int b = 0; b < 8; ++b)
                T[b] = (g8 ? ub[b] : ua[b]) + dppf<0x128>(g8 ? ua[b] : ub[b]);
            float V[4];
#pragma unroll
            for (int i = 0; i < 4; ++i)
                V[i] = (e4 ? T[i+4] : T[i]) + dppf<0x141>(e4 ? T[i] : T[i+4]);
            float X[2];
#pragma unroll
            for (int i = 0; i < 2; ++i)
                X[i] = (e2 ? V[i+2] : V[i]) + dppf<0x4E>(e2 ? V[i] : V[i+2]);
            DB = (e1 ? X[1] : X[0]) + dppf<0xB1>(e1 ? X[0] : X[1]);
            EB = dppf<0x128>(DB);
        }
        // lanes s2<8: i=DA, f=EA, g=DB, o=EB; lanes s2>=8: i=EA, f=DA, g=EB, o=DB (b = s2&7)

        const float gi2 = lowh ? DA : EA;
        const float gf2 = lowh ? EA : DA;
        const float gg2 = lowh ? DB : EB;
        const float go2 = lowh ? EB : DB;
        const float i2 = sigm(gi2), f2g = sigm(gf2), g2v = tanhf_(gg2), o2 = sigm(go2);
        c2 = f2g * c2 + i2 * g2v;                 // both lane-halves keep identical c2
        const float h2n = o2 * tanhf_(c2);
        // fused FC into LDS accumulators, classes split: lower lanes 0..5, upper 6..10
        if (packed) {
            const float* fp = wfcPk + (t << 10);
            const float4 fa = *(const float4*)fp;
            const float2 fb = *(const float2*)(fp + 4);
            lfacc[tid][0] += h2n * fa.x;
            lfacc[tid][1] += h2n * fa.y;
            lfacc[tid][2] += h2n * fa.z;
            lfacc[tid][3] += h2n * fa.w;
            lfacc[tid][4] += h2n * fb.x;
            if (lowh) lfacc[tid][5] += h2n * fb.y;
        } else {
            const float* wfcp = Wfc + t * 64 + d2 + (lowh ? 0 : 6 * 8192);
            if (lowh) {
#pragma unroll
                for (int c = 0; c < 6; ++c) lfacc[tid][c] += h2n * wfcp[c * 8192];
            } else {
#pragma unroll
                for (int c = 0; c < 5; ++c) lfacc[tid][c] += h2n * wfcp[c * 8192];
            }
        }
        if (lowh) lh2[tb][s2][d2] = h2n;   // double-buffered: next read is after B(t+1)
    }

    // final FC reduction: pull per-thread accumulators back to regs, sum over the
    // 4 in-wave d2 groups (lane bits 4,5 — cross-row, keep __shfl_xor), then
    // across the 16 waves via LDS.
    float facc[6];
#pragma unroll
    for (int c = 0; c < 6; ++c) facc[c] = lfacc[tid][c];
#pragma unroll
    for (int c = 0; c < 6; ++c) {
        facc[c] += __shfl_xor(facc[c], 16);
        facc[c] += __shfl_xor(facc[c], 32);
    }
    const int wv = tid >> 6;
    if ((tid & 63) < 16) {
        const int bb = tid & 7;
        if ((tid & 15) < 8) {
#pragma unroll
            for (int c = 0; c < 6; ++c) fpart[wv][bb][c] = facc[c];
        } else {
#pragma unroll
            for (int c = 0; c < 5; ++c) fpart[wv][bb][6 + c] = facc[c];
        }
    }
    __syncthreads();
    if (tid < BTILE * NCLS) {
        const int bb = tid / NCLS, c = tid - bb * NCLS;
        float v = bfc[c];
#pragma unroll
        for (int w = 0; w < 16; ++w) v += fpart[w][bb][c];
        out[(b0 + bb) * NCLS + c] = v;
    }
}

extern "C" void kernel_launch(void* const* d_in, const int* in_sizes, int n_in,
                              void* d_out, int out_size, void* d_ws, size_t ws_size,
                              hipStream_t stream) {
    const float* x    = (const float*)d_in[0];
    const float* Wih1 = (const float*)d_in[1];
    const float* Whh1 = (const float*)d_in[2];
    const float* Wih2 = (const float*)d_in[3];
    const float* Whh2 = (const float*)d_in[4];
    const float* Wfc  = (const float*)d_in[5];
    const float* bfc  = (const float*)d_in[6];
    float* out = (float*)d_out;
    float* ws  = (float*)d_ws;

    const int packed = (ws_size >= (size_t)(WTOT + WFCF) * 4) ? 1 : 0;
    const int prep_elems = WTOT + (packed ? WFCF : 0);   // 448 KB (+512 KB packed FC)
    prep_weights<<<(prep_elems + 255) / 256, 256, 0, stream>>>(Whh1, Wih2, Whh2, Wfc, ws, packed);
    lstm_fused_t<<<256, 1024, 0, stream>>>(x, Wih1, Wfc, bfc, ws, out, packed);
}